// Round 14
// baseline (279.740 us; speedup 1.0000x reference)
//
#include <hip/hip_runtime.h>
#include <hip/hip_bf16.h>
#include <stdint.h>

typedef short short8 __attribute__((ext_vector_type(8)));
typedef float f32x4 __attribute__((ext_vector_type(4)));
typedef float fvec4 __attribute__((ext_vector_type(4)));
typedef unsigned short us4 __attribute__((ext_vector_type(4)));
typedef unsigned short us8 __attribute__((ext_vector_type(8)));

// native float->bf16 (RNE)
static __device__ __forceinline__ unsigned short f2bf(float f) {
  return __bfloat16_as_ushort(__float2bfloat16(f));
}

static __device__ __forceinline__ float bf2f(unsigned short u) {
  union { uint32_t u; float f; } v; v.u = (uint32_t)u << 16;
  return v.f;
}

// fast ELU: __expf -> v_exp_f32. |err| ~1e-7, fine vs 2e-2 threshold.
static __device__ __forceinline__ float elu_f(float v) {
  return v > 0.0f ? v : __expf(v) - 1.0f;
}

// Fused prep, four concurrent block ranges:
//   [0, 1024)                 : pack all 4 weights into MFMA B-fragment order
//   [1024, 1024+hb)           : histogram dst counts
//   [1024+hb, 1024+hb+zb)     : zero agg (N*256 f32)
//   [1024+hb+zb, ...)         : convert x (f32) -> xH (bf16)
__global__ void prep_kernel(const float* __restrict__ W1a, const float* __restrict__ W1b,
                            const float* __restrict__ W2a, const float* __restrict__ W2b,
                            unsigned short* __restrict__ w1aP, unsigned short* __restrict__ w1bP,
                            unsigned short* __restrict__ w2aP, unsigned short* __restrict__ w2bP,
                            const int* __restrict__ col_idx, int* __restrict__ cnt, int E,
                            float* __restrict__ agg, int aggN, int hb, int zb,
                            const float* __restrict__ x, unsigned short* __restrict__ xH,
                            int xElems) {
  int b = blockIdx.x;
  if (b < 1024) {
    int p = b * 256 + threadIdx.x;
    const float* W; unsigned short* dst; int KT, Nc, q;
    if (p < 65536)       { W = W1a; dst = w1aP; KT = 8;  Nc = 256; q = p; }
    else if (p < 131072) { W = W1b; dst = w1bP; KT = 8;  Nc = 256; q = p - 65536; }
    else if (p < 229376) { W = W2a; dst = w2aP; KT = 12; Nc = 256; q = p - 131072; }
    else                 { W = W2b; dst = w2bP; KT = 8;  Nc = 128; q = p - 229376; }
    int i = q & 7;
    int l = (q >> 3) & 63;
    int rest = q >> 9;
    int kt = rest % KT;
    int nt = rest / KT;
    dst[q] = f2bf(W[(size_t)(kt * 32 + (l >> 4) * 8 + i) * Nc + nt * 16 + (l & 15)]);
  } else if (b < 1024 + hb) {
    int i = (b - 1024) * 256 + threadIdx.x;
    if (i < E) atomicAdd(&cnt[col_idx[i]], 1);
  } else if (b < 1024 + hb + zb) {
    int idx = (b - 1024 - hb) * 256 + threadIdx.x;  // fvec4 index
    if (idx * 4 < aggN) {
      fvec4 z = {0.f, 0.f, 0.f, 0.f};
      *(fvec4*)(agg + (size_t)idx * 4) = z;
    }
  } else {
    int idx = (b - 1024 - hb - zb) * 256 + threadIdx.x;  // 8-float chunk index
    if (idx * 8 < xElems) {
      const float* src = x + (size_t)idx * 8;
      fvec4 a = *(const fvec4*)src;
      fvec4 c = *(const fvec4*)(src + 4);
      us8 o;
      o[0] = f2bf(a.x); o[1] = f2bf(a.y); o[2] = f2bf(a.z); o[3] = f2bf(a.w);
      o[4] = f2bf(c.x); o[5] = f2bf(c.y); o[6] = f2bf(c.z); o[7] = f2bf(c.w);
      *(us8*)(xH + (size_t)idx * 8) = o;
    }
  }
}

// single-launch scan: each thread serially owns a chunk, one 1024-wide block scan.
__global__ __launch_bounds__(1024) void scan_kernel(const int* __restrict__ cnt,
                                                    int* __restrict__ startA,
                                                    int* __restrict__ offs, int N, int E) {
  __shared__ int partial[1024];
  const int t = threadIdx.x;
  const int chunk = (N + 1023) >> 10;
  const int base = t * chunk;
  int s = 0;
  for (int i = 0; i < chunk; ++i) {
    int idx = base + i;
    if (idx < N) s += cnt[idx];
  }
  partial[t] = s;
  __syncthreads();
  for (int o = 1; o < 1024; o <<= 1) {
    int a = (t >= o) ? partial[t - o] : 0;
    __syncthreads();
    partial[t] += a;
    __syncthreads();
  }
  int run = partial[t] - s;
  for (int i = 0; i < chunk; ++i) {
    int idx = base + i;
    if (idx < N) {
      startA[idx] = run;
      offs[idx] = run;
      run += cnt[idx];
    }
  }
  if (t == 0) startA[N] = E;
}

// Permute+convert pass: read eattr SEQUENTIALLY (nontemporal, full BW), write
// bf16 rows to CSR slot rank (scattered 256B full-line writes, L3-resident).
// Also emits rowS/dstS so the edge kernel has zero indirect index chains.
__global__ __launch_bounds__(256) void scatter_kernel(
    const int* __restrict__ row_idx, const int* __restrict__ col_idx,
    const float* __restrict__ eattr, int* __restrict__ offs,
    int* __restrict__ rowS, int* __restrict__ dstS,
    unsigned short* __restrict__ eattrS, int E) {
  __shared__ int rr[64];
  const int t = threadIdx.x;
  const int e0 = blockIdx.x * 64;

  if (t < 64) {
    int e = e0 + t;
    int d = col_idx[e];
    int r = atomicAdd(&offs[d], 1);
    rr[t] = r;
    rowS[r] = row_idx[e];
    dstS[r] = d;
  }
  __syncthreads();

  // 64 edges x 16 chunks of 8 floats -> 8 bf16 (16B) each
  for (int idx = t; idx < 64 * 16; idx += 256) {
    int e = idx >> 4, c = idx & 15;
    const fvec4* src = (const fvec4*)(eattr + (size_t)(e0 + e) * 128 + c * 8);
    fvec4 a = __builtin_nontemporal_load(src);
    fvec4 b = __builtin_nontemporal_load(src + 1);
    us8 o;
    o[0] = f2bf(a.x); o[1] = f2bf(a.y); o[2] = f2bf(a.z); o[3] = f2bf(a.w);
    o[4] = f2bf(b.x); o[5] = f2bf(b.y); o[6] = f2bf(b.z); o[7] = f2bf(b.w);
    *(us8*)(eattrS + (size_t)rr[e] * 128 + c * 8) = o;
  }
}

#define LDA 264  // 256 + 8 pad (bf16 elems); 528B row stride, 16B aligned
#define EBR 32   // CSR slots per block

// 32 dst-sorted CSR slots/block, 4 waves; wave w owns output cols [64w,64w+64),
// acc[2][4]. All inputs pre-converted bf16: eattrS read SEQUENTIALLY by slot,
// xH gathered (6.4MB, cache-resident). Staging = pure 16B copies, no converts.
// GEMM1 + ELU + segmented reduce (W1b applied post-mean in node kernel).
__global__ __launch_bounds__(256, 6) void edge_mlp_kernel(
    const unsigned short* __restrict__ xH, const int* __restrict__ rowS,
    const int* __restrict__ dstS, const unsigned short* __restrict__ eattrS,
    const float* __restrict__ b1a, const unsigned short* __restrict__ w1aP,
    float* __restrict__ agg) {
  __shared__ __align__(16) unsigned short As[EBR * LDA];
  __shared__ int rowi[EBR];
  __shared__ int dsts[EBR];
  const int t = threadIdx.x;
  const int e0 = blockIdx.x * EBR;

  if (t < EBR) {
    rowi[t] = rowS[e0 + t];   // sequential reads
    dsts[t] = dstS[e0 + t];   // non-decreasing across the tile (CSR order)
  }

  const int w = t >> 6, l = t & 63;
  const int lr = l & 15, lk = l >> 4;
  const unsigned short* B1 = w1aP + (size_t)(w * 32) * 512 + (size_t)l * 8;

  short8 bA[4], bB[4];
#pragma unroll
  for (int n = 0; n < 4; ++n) bA[n] = *(const short8*)(B1 + n * 4096);

  __syncthreads();

  // stage A: [32 slots][256 bf16] = (xH[rowS] | eattrS[slot]) -- pure 16B copies
  for (int idx = t; idx < EBR * 32; idx += 256) {
    int e = idx >> 5, g = idx & 31;
    us8 v;
    if (g < 16)
      v = *(const us8*)(xH + (size_t)rowi[e] * 128 + g * 8);
    else
      v = *(const us8*)(eattrS + (size_t)(e0 + e) * 128 + (g - 16) * 8);
    *(us8*)(&As[e * LDA + g * 8]) = v;
  }
  __syncthreads();

  f32x4 acc[2][4];
  const f32x4 zero4 = {0.f, 0.f, 0.f, 0.f};
#pragma unroll
  for (int mt = 0; mt < 2; ++mt)
#pragma unroll
    for (int nt = 0; nt < 4; ++nt) acc[mt][nt] = zero4;

  // GEMM1: [32,256] x W1a[256,256], B double-buffered
#pragma unroll
  for (int kt = 0; kt < 8; ++kt) {
    short8* bc = (kt & 1) ? bB : bA;
    short8* bn = (kt & 1) ? bA : bB;
    if (kt < 7) {
#pragma unroll
      for (int n = 0; n < 4; ++n) bn[n] = *(const short8*)(B1 + n * 4096 + (kt + 1) * 512);
    }
    short8 a[2];
#pragma unroll
    for (int mt = 0; mt < 2; ++mt)
      a[mt] = *(const short8*)(&As[(mt * 16 + lr) * LDA + kt * 32 + lk * 8]);
#pragma unroll
    for (int mt = 0; mt < 2; ++mt)
#pragma unroll
      for (int nt = 0; nt < 4; ++nt)
        acc[mt][nt] = __builtin_amdgcn_mfma_f32_16x16x32_bf16(a[mt], bc[nt], acc[mt][nt], 0, 0, 0);
  }
  __syncthreads();  // all waves done reading As

  // epilogue: bias + ELU -> bf16 back into As
#pragma unroll
  for (int nt = 0; nt < 4; ++nt) {
    int col = w * 64 + nt * 16 + lr;
    float bias = b1a[col];
#pragma unroll
    for (int mt = 0; mt < 2; ++mt)
#pragma unroll
      for (int j = 0; j < 4; ++j) {
        float v = elu_f(acc[mt][nt][j] + bias);
        As[(mt * 16 + lk * 4 + j) * LDA + col] = f2bf(v);
      }
  }
  __syncthreads();

  // segmented reduction over dst-runs; thread t owns column t.
  {
    const int col = t;
    float run = 0.f;
    int prev = dsts[0];
    int segstart = 0;
#pragma unroll 8
    for (int r = 0; r < EBR; ++r) {
      int d = dsts[r];
      if (d != prev) {
        if (segstart == 0)
          atomicAdd(&agg[(size_t)prev * 256 + col], run);
        else
          agg[(size_t)prev * 256 + col] = run;  // interior: sole owner
        run = 0.f;
        prev = d;
        segstart = r;
      }
      run += bf2f(As[r * LDA + col]);
    }
    atomicAdd(&agg[(size_t)prev * 256 + col], run);  // tail touches tile edge
  }
}

#define LDN 392  // 384 + 8 pad

// 64 nodes/block, 4 waves. [proven: unchanged since R10]
__global__ __launch_bounds__(256, 3) void node_mlp_kernel(
    const float* __restrict__ x, const float* __restrict__ agg,
    const int* __restrict__ startA, const float* __restrict__ b1b,
    const float* __restrict__ b2a, const float* __restrict__ b2b,
    const unsigned short* __restrict__ w1bP, const unsigned short* __restrict__ w2aP,
    const unsigned short* __restrict__ w2bP,
    float* __restrict__ out, int N) {
  __shared__ __align__(16) unsigned short As[64 * LDN];
  __shared__ float inv64[64];
  const int t = threadIdx.x;
  const int n0 = blockIdx.x * 64;

  const int w = t >> 6, l = t & 63;
  const int lr = l & 15, lk = l >> 4;
  const unsigned short* B0 = w1bP + (size_t)(w * 32) * 512 + (size_t)l * 8;
  const unsigned short* B1 = w2aP + (size_t)(w * 48) * 512 + (size_t)l * 8;
  const unsigned short* B2 = w2bP + (size_t)(w * 16) * 512 + (size_t)l * 8;

  if (t < 64) {
    int node = n0 + t;
    int cn = (node < N) ? (startA[node + 1] - startA[node]) : 0;
    inv64[t] = cn > 0 ? 1.0f / (float)cn : 0.f;
  }

  short8 bA[4], bB[4];
#pragma unroll
  for (int n = 0; n < 4; ++n) bA[n] = *(const short8*)(B0 + n * 4096);

  __syncthreads();  // inv64 ready

  // stage magg: [64][264] bf16 = agg[node]*inv
  for (int idx = t; idx < 64 * 64; idx += 256) {
    int nn = idx >> 6, c4 = idx & 63;
    int node = n0 + nn;
    fvec4 v = {0.f, 0.f, 0.f, 0.f};
    if (node < N) {
      float inv = inv64[nn];
      fvec4 a = *(const fvec4*)(agg + (size_t)node * 256 + c4 * 4);
      v.x = a.x * inv; v.y = a.y * inv; v.z = a.z * inv; v.w = a.w * inv;
    }
    us4 o;
    o.x = f2bf(v.x); o.y = f2bf(v.y); o.z = f2bf(v.z); o.w = f2bf(v.w);
    *(us4*)(&As[nn * 264 + c4 * 4]) = o;
  }
  __syncthreads();

  const f32x4 zero4 = {0.f, 0.f, 0.f, 0.f};
  f32x4 accU[4][4];
#pragma unroll
  for (int mt = 0; mt < 4; ++mt)
#pragma unroll
    for (int nt = 0; nt < 4; ++nt) accU[mt][nt] = zero4;

  // GEMM-u: magg[64,256] x W1b[256,256]
#pragma unroll
  for (int kt = 0; kt < 8; ++kt) {
    short8* bc = (kt & 1) ? bB : bA;
    short8* bn = (kt & 1) ? bA : bB;
    if (kt < 7) {
#pragma unroll
      for (int n = 0; n < 4; ++n) bn[n] = *(const short8*)(B0 + n * 4096 + (kt + 1) * 512);
    }
    short8 a[4];
#pragma unroll
    for (int mt = 0; mt < 4; ++mt)
      a[mt] = *(const short8*)(&As[(mt * 16 + lr) * 264 + kt * 32 + lk * 8]);
#pragma unroll
    for (int mt = 0; mt < 4; ++mt)
#pragma unroll
      for (int nt = 0; nt < 4; ++nt)
        accU[mt][nt] = __builtin_amdgcn_mfma_f32_16x16x32_bf16(a[mt], bc[nt], accU[mt][nt], 0, 0, 0);
  }

  // prefetch W2a kt=0
#pragma unroll
  for (int n = 0; n < 4; ++n) bA[n] = *(const short8*)(B1 + n * 6144);

  __syncthreads();  // magg reads done; As re-purposed at stride 392

  // stage x into cols [0,128) of the [64][392] buffer
  for (int idx = t; idx < 64 * 32; idx += 256) {
    int nn = idx >> 5, c4 = idx & 31;
    int node = n0 + nn;
    fvec4 v = {0.f, 0.f, 0.f, 0.f};
    if (node < N) v = *(const fvec4*)(x + (size_t)node * 128 + c4 * 4);
    us4 o;
    o.x = f2bf(v.x); o.y = f2bf(v.y); o.z = f2bf(v.z); o.w = f2bf(v.w);
    *(us4*)(&As[nn * LDN + c4 * 4]) = o;
  }

  // write u = accU + b1b (gated by cnt>0) into cols [128,384)
#pragma unroll
  for (int nt = 0; nt < 4; ++nt) {
    int col = w * 64 + nt * 16 + lr;
    float bias = b1b[col];
#pragma unroll
    for (int mt = 0; mt < 4; ++mt)
#pragma unroll
      for (int j = 0; j < 4; ++j) {
        int row = mt * 16 + lk * 4 + j;
        float g = inv64[row] > 0.f ? 1.f : 0.f;
        As[row * LDN + 128 + col] = f2bf(accU[mt][nt][j] + g * bias);
      }
  }
  __syncthreads();

  f32x4 acc[4][4];
#pragma unroll
  for (int mt = 0; mt < 4; ++mt)
#pragma unroll
    for (int nt = 0; nt < 4; ++nt) acc[mt][nt] = zero4;

  // MLP2 GEMM1: [64,384] x W2a[384,256]
#pragma unroll
  for (int kt = 0; kt < 12; ++kt) {
    short8* bc = (kt & 1) ? bB : bA;
    short8* bn = (kt & 1) ? bA : bB;
    if (kt < 11) {
#pragma unroll
      for (int n = 0; n < 4; ++n) bn[n] = *(const short8*)(B1 + n * 6144 + (kt + 1) * 512);
    }
    short8 a[4];
#pragma unroll
    for (int mt = 0; mt < 4; ++mt)
      a[mt] = *(const short8*)(&As[(mt * 16 + lr) * LDN + kt * 32 + lk * 8]);
#pragma unroll
    for (int mt = 0; mt < 4; ++mt)
#pragma unroll
      for (int nt = 0; nt < 4; ++nt)
        acc[mt][nt] = __builtin_amdgcn_mfma_f32_16x16x32_bf16(a[mt], bc[nt], acc[mt][nt], 0, 0, 0);
  }

#pragma unroll
  for (int n = 0; n < 2; ++n) bA[n] = *(const short8*)(B2 + n * 4096);

  __syncthreads();

  // epilogue1: bias + ELU -> H (reuse As, stride 264)
#pragma unroll
  for (int nt = 0; nt < 4; ++nt) {
    int col = w * 64 + nt * 16 + lr;
    float bias = b2a[col];
#pragma unroll
    for (int mt = 0; mt < 4; ++mt)
#pragma unroll
      for (int j = 0; j < 4; ++j) {
        float v = elu_f(acc[mt][nt][j] + bias);
        As[(mt * 16 + lk * 4 + j) * 264 + col] = f2bf(v);
      }
  }
  __syncthreads();

  // GEMM2: H[64,256] x W2b[256,128]; wave w owns cols [32w, 32w+32)
  f32x4 acc2[4][2];
#pragma unroll
  for (int mt = 0; mt < 4; ++mt)
#pragma unroll
    for (int nt = 0; nt < 2; ++nt) acc2[mt][nt] = zero4;
#pragma unroll
  for (int kt = 0; kt < 8; ++kt) {
    short8* bc = (kt & 1) ? bB : bA;
    short8* bn = (kt & 1) ? bA : bB;
    if (kt < 7) {
#pragma unroll
      for (int n = 0; n < 2; ++n) bn[n] = *(const short8*)(B2 + n * 4096 + (kt + 1) * 512);
    }
    short8 a[4];
#pragma unroll
    for (int mt = 0; mt < 4; ++mt)
      a[mt] = *(const short8*)(&As[(mt * 16 + lr) * 264 + kt * 32 + lk * 8]);
#pragma unroll
    for (int mt = 0; mt < 4; ++mt)
#pragma unroll
      for (int nt = 0; nt < 2; ++nt)
        acc2[mt][nt] = __builtin_amdgcn_mfma_f32_16x16x32_bf16(a[mt], bc[nt], acc2[mt][nt], 0, 0, 0);
  }

  // epilogue2: bias + store
#pragma unroll
  for (int nt = 0; nt < 2; ++nt) {
    int col = w * 32 + nt * 16 + lr;
    float bias = b2b[col];
#pragma unroll
    for (int mt = 0; mt < 4; ++mt)
#pragma unroll
      for (int j = 0; j < 4; ++j) {
        int node = n0 + mt * 16 + lk * 4 + j;
        if (node < N) out[(size_t)node * 128 + col] = acc2[mt][nt][j] + bias;
      }
  }
}

extern "C" void kernel_launch(void* const* d_in, const int* in_sizes, int n_in,
                              void* d_out, int out_size, void* d_ws, size_t ws_size,
                              hipStream_t stream) {
  const float* x = (const float*)d_in[0];
  const int* ei = (const int*)d_in[1];
  const float* eattr = (const float*)d_in[2];
  const float* W1a = (const float*)d_in[5];
  const float* b1a = (const float*)d_in[6];
  const float* W1b = (const float*)d_in[7];
  const float* b1b = (const float*)d_in[8];
  const float* W2a = (const float*)d_in[9];
  const float* b2a = (const float*)d_in[10];
  const float* W2b = (const float*)d_in[11];
  const float* b2b = (const float*)d_in[12];

  const int N = in_sizes[0] / 128;   // 25000
  const int E = in_sizes[2] / 128;   // 400000

  char* ws = (char*)d_ws;
  float* agg = (float*)ws;                              // N*256 f32 (sum of elu(h1))
  size_t off = (size_t)N * 256 * 4;
  int* cntbuf = (int*)(ws + off); off += (size_t)N * 4;
  int* startA = (int*)(ws + off); off += (size_t)(N + 1) * 4;
  int* offs   = (int*)(ws + off); off += (size_t)N * 4;
  int* rowS   = (int*)(ws + off); off += (size_t)E * 4;
  int* dstS   = (int*)(ws + off); off += (size_t)E * 4;
  off = (off + 255) & ~(size_t)255;
  unsigned short* xH     = (unsigned short*)(ws + off); off += (size_t)N * 128 * 2;
  off = (off + 255) & ~(size_t)255;
  unsigned short* eattrS = (unsigned short*)(ws + off); off += (size_t)E * 128 * 2;
  unsigned short* w1aP = (unsigned short*)(ws + off); off += 256 * 256 * 2;
  unsigned short* w1bP = (unsigned short*)(ws + off); off += 256 * 256 * 2;
  unsigned short* w2aP = (unsigned short*)(ws + off); off += 384 * 256 * 2;
  unsigned short* w2bP = (unsigned short*)(ws + off);

  // zero only cnt via memset (100 KB); agg zeroing runs inside prep.
  (void)hipMemsetAsync(cntbuf, 0, (size_t)N * 4, stream);

  const int hb = (E + 255) / 256;                  // hist blocks
  const int aggN = N * 256;                        // f32 elements in agg
  const int zb = (aggN / 4 + 255) / 256;           // agg-zero blocks
  const int xElems = N * 128;
  const int xb = (xElems / 8 + 255) / 256;         // x-convert blocks

  prep_kernel<<<1024 + hb + zb + xb, 256, 0, stream>>>(
      W1a, W1b, W2a, W2b, w1aP, w1bP, w2aP, w2bP, ei + E, cntbuf, E,
      agg, aggN, hb, zb, x, xH, xElems);

  scan_kernel<<<1, 1024, 0, stream>>>(cntbuf, startA, offs, N, E);

  scatter_kernel<<<E / 64, 256, 0, stream>>>(ei, ei + E, eattr, offs,
                                             rowS, dstS, eattrS, E);

  edge_mlp_kernel<<<E / EBR, 256, 0, stream>>>(xH, rowS, dstS, eattrS, b1a, w1aP, agg);

  node_mlp_kernel<<<(N + 63) / 64, 256, 0, stream>>>(x, agg, startA, b1b, b2a, b2b,
                                                     w1bP, w2aP, w2bP, (float*)d_out, N);
}